// Round 9
// baseline (262.373 us; speedup 1.0000x reference)
//
#include <hip/hip_runtime.h>
#include <math.h>

#define IN_F  128
#define HID   96
#define OUT_F 40
#define MASKD 64

#define PBITS 8
#define PSIZE 256          // nodes per partition (requires n <= 65536)
#define CHUNK 2048         // edges per workgroup in binning passes

typedef unsigned int uint;
typedef unsigned short ushort;

// bf16 helpers. CONSTRAINT (R7 failure): h-path messages (hs) MUST stay fp32 —
// bf16 hs perturbs prob by ~2.5e-3 and flips mask=(prob>0.5) hard bits
// (Output 2 absmax=1.0). bf16 is safe ONLY for zs (logits-only path, 5x margin).
__device__ inline float bflo(uint u) { return __uint_as_float(u << 16); }
__device__ inline float bfhi(uint u) { return __uint_as_float(u & 0xffff0000u); }
__device__ inline ushort f2bf(float f) {        // round-to-nearest-even
    uint u = __float_as_uint(f);
    u += 0x7fff + ((u >> 16) & 1);
    return (ushort)(u >> 16);
}

// ======================= partition-local CSR construction =======================
__global__ void k_pzero(int* __restrict__ part_total) {
    part_total[threadIdx.x] = 0;
}

__global__ void k_pcount(const int* __restrict__ dst, int* __restrict__ part_total, int e) {
    __shared__ int hist[256];
    hist[threadIdx.x] = 0;
    __syncthreads();
    int start = blockIdx.x * CHUNK, end = min(e, start + CHUNK);
    for (int i = start + threadIdx.x; i < end; i += 256)
        atomicAdd(&hist[dst[i] >> PBITS], 1);
    __syncthreads();
    int v = hist[threadIdx.x];
    if (v) atomicAdd(&part_total[threadIdx.x], v);
}

__global__ void k_pscan(const int* __restrict__ part_total, int* __restrict__ part_base,
                        int* __restrict__ part_cursor, int np) {
    __shared__ int tmp[256];
    int tid = threadIdx.x;
    int v = (tid < np) ? part_total[tid] : 0;
    tmp[tid] = v;
    __syncthreads();
    for (int d = 1; d < 256; d <<= 1) {
        int t = (tid >= d) ? tmp[tid - d] : 0;
        __syncthreads();
        tmp[tid] += t;
        __syncthreads();
    }
    int excl = tmp[tid] - v;
    if (tid < np) { part_base[tid] = excl; part_cursor[tid] = excl; }
    if (tid == 255) part_base[np] = tmp[255];   // total = e
}

// bin edges into partition-sorted ebuf; packed 4B/edge: src(16b) | dst_local(8b)<<16
// (exact: src < n <= 65536)
__global__ __launch_bounds__(256) void k_bin(const int* __restrict__ src,
                                             const int* __restrict__ dst,
                                             int* __restrict__ part_cursor,
                                             uint* __restrict__ ebuf, int e) {
    __shared__ int hist[256];
    __shared__ int cur[256];
    int tid = threadIdx.x;
    hist[tid] = 0;
    __syncthreads();
    int start = blockIdx.x * CHUNK, end = min(e, start + CHUNK);
    for (int i = start + tid; i < end; i += 256)
        atomicAdd(&hist[dst[i] >> PBITS], 1);
    __syncthreads();
    int hv = hist[tid];
    cur[tid] = hv ? atomicAdd(&part_cursor[tid], hv) : 0;
    __syncthreads();
    for (int i = start + tid; i < end; i += 256) {
        int d = dst[i];
        int pos = atomicAdd(&cur[d >> PBITS], 1);
        ebuf[pos] = (uint)src[i] | ((uint)(d & (PSIZE - 1)) << 16);
    }
}

// one workgroup per partition: LDS count + scan + LDS-cursor fill; emits deg/offs/dinv.
__global__ __launch_bounds__(256) void k_csr(const uint* __restrict__ ebuf,
                                             const int* __restrict__ part_base,
                                             int* __restrict__ deg, int* __restrict__ offs,
                                             float* __restrict__ dinv,
                                             int* __restrict__ csr, int n) {
    __shared__ int cnt[256];
    __shared__ int tmp[256];
    __shared__ int cur[256];
    int tid = threadIdx.x;
    int p = blockIdx.x;
    int ebase = part_base[p], eend = part_base[p + 1];
    cnt[tid] = 0;
    __syncthreads();
    for (int i = ebase + tid; i < eend; i += 256)
        atomicAdd(&cnt[(ebuf[i] >> 16) & 255], 1);
    __syncthreads();
    int v = cnt[tid];
    tmp[tid] = v;
    __syncthreads();
    for (int d = 1; d < 256; d <<= 1) {
        int t = (tid >= d) ? tmp[tid - d] : 0;
        __syncthreads();
        tmp[tid] += t;
        __syncthreads();
    }
    int goff = ebase + (tmp[tid] - v);
    int node = p * PSIZE + tid;
    if (node < n) {
        deg[node] = v;
        offs[node] = goff;
        dinv[node] = rsqrtf((float)(v + 1));
    }
    cur[tid] = goff;
    __syncthreads();
    for (int i = ebase + tid; i < eend; i += 256) {
        uint ed = ebuf[i];
        int pos = atomicAdd(&cur[(ed >> 16) & 255], 1);
        csr[pos] = (int)(ed & 0xffffu);
    }
}

// ======================= GEMM1: hs = (x @ W1) * dinv[row]  (fp32, 4x4 register tiles) ===============
// R8 profile: 47us, Occupancy 12.5%, VALUBusy 20% — latency-bound at 64KB LDS
// (<=6 waves/CU) + un-padded sx bank collisions (3.2M conflict cycles).
// R9: 64 rows x 384 threads; W staged in two 24KB K-halves (LDS 57KB -> 2 blocks
// = 12 waves/CU); sx padded to 132 floats/row (stride % 32 banks != 0, 16B-aligned).
// #pragma unroll 1 on the k-loop is load-bearing (R3: full unroll -> VGPR=256 spill).
#define G1_ROWS 64
#define SXLD   132
__global__ __launch_bounds__(384) void k_gemm1(const float* __restrict__ x,
                                               const float* __restrict__ W1,
                                               const float* __restrict__ dinv,
                                               float* __restrict__ hs, int n) {
    __shared__ float sW[64 * HID];          // 24 KB, one K-half, [k][c]
    __shared__ float sx[G1_ROWS * SXLD];    // 33 KB, [r][k] padded
    int tid = threadIdx.x;
    int base = blockIdx.x * G1_ROWS;
    int nt = min(G1_ROWS, n - base);
    for (int i = tid; i < nt * (IN_F / 4); i += 384) {
        int r = i >> 5, kq = i & 31;
        ((float4*)(sx + r * SXLD))[kq] = ((const float4*)(x + (size_t)(base + r) * IN_F))[kq];
    }
    int rt = tid / 24, ct = tid % 24;   // 16 rt x 4 rows, 24 ct x 4 cols
    float acc[4][4] = {};
    for (int kh = 0; kh < 2; kh++) {
        __syncthreads();   // sx ready (kh=0) / sW half no longer read (kh=1)
        for (int i = tid; i < 64 * HID / 4; i += 384)
            ((float4*)sW)[i] = ((const float4*)(W1 + kh * 64 * HID))[i];
        __syncthreads();
#pragma unroll 1
        for (int k0 = 0; k0 < 64; k0 += 4) {
            float4 xv[4], wv[4];
#pragma unroll
            for (int i = 0; i < 4; i++)
                xv[i] = *(const float4*)&sx[(rt * 4 + i) * SXLD + kh * 64 + k0];
#pragma unroll
            for (int j = 0; j < 4; j++)
                wv[j] = *(const float4*)&sW[(k0 + j) * HID + ct * 4];
#pragma unroll
            for (int j = 0; j < 4; j++) {
                float4 w = wv[j];
#pragma unroll
                for (int i = 0; i < 4; i++) {
                    float xs = (j == 0) ? xv[i].x : (j == 1) ? xv[i].y : (j == 2) ? xv[i].z : xv[i].w;
                    acc[i][0] += xs * w.x;
                    acc[i][1] += xs * w.y;
                    acc[i][2] += xs * w.z;
                    acc[i][3] += xs * w.w;
                }
            }
        }
    }
#pragma unroll
    for (int i = 0; i < 4; i++) {
        int r = rt * 4 + i;
        if (r < nt) {
            int node = base + r;
            float dv = dinv[node];
            float4 o = {acc[i][0] * dv, acc[i][1] * dv, acc[i][2] * dv, acc[i][3] * dv};
            *(float4*)(hs + (size_t)node * HID + ct * 4) = o;
        }
    }
}

// ======================= gather1 + relu: h = relu(agg * dinv + b1)  (fp32 messages) =================
__global__ __launch_bounds__(256) void k_gather1(const int* __restrict__ offs,
                                                 const int* __restrict__ deg,
                                                 const int* __restrict__ csr,
                                                 const float* __restrict__ hs,
                                                 const float* __restrict__ dinv,
                                                 const float* __restrict__ b1,
                                                 float* __restrict__ h, int n) {
    int t = blockIdx.x * 256 + threadIdx.x;
    int node = t >> 5, cg = t & 31;
    if (node >= n || cg >= 24) return;
    int o = offs[node], cnt = deg[node];
    size_t col = (size_t)cg * 4;
    float4 acc = *(const float4*)(hs + (size_t)node * HID + col);  // self-loop term
    int k = o, kend = o + cnt;
    for (; k + 3 < kend; k += 4) {
        int s0 = csr[k], s1 = csr[k + 1], s2 = csr[k + 2], s3 = csr[k + 3];
        const float4 v0 = *(const float4*)(hs + (size_t)s0 * HID + col);
        const float4 v1 = *(const float4*)(hs + (size_t)s1 * HID + col);
        const float4 v2 = *(const float4*)(hs + (size_t)s2 * HID + col);
        const float4 v3 = *(const float4*)(hs + (size_t)s3 * HID + col);
        acc.x += (v0.x + v1.x) + (v2.x + v3.x);
        acc.y += (v0.y + v1.y) + (v2.y + v3.y);
        acc.z += (v0.z + v1.z) + (v2.z + v3.z);
        acc.w += (v0.w + v1.w) + (v2.w + v3.w);
    }
    for (; k < kend; k++) {
        int s0 = csr[k];
        const float4 v0 = *(const float4*)(hs + (size_t)s0 * HID + col);
        acc.x += v0.x; acc.y += v0.y; acc.z += v0.z; acc.w += v0.w;
    }
    float dv = dinv[node];
    float4 bv = *(const float4*)(b1 + col);
    float4 o4 = {fmaxf(acc.x * dv + bv.x, 0.f), fmaxf(acc.y * dv + bv.y, 0.f),
                 fmaxf(acc.z * dv + bv.z, 0.f), fmaxf(acc.w * dv + bv.w, 0.f)};
    *(float4*)(h + (size_t)node * HID + col) = o4;
}

// ======================= GEMM2: zs = bf16((h @ W2) * dinv[row]) =======================
#define G2_ROWS 96
__global__ __launch_bounds__(256) void k_gemm2(const float* __restrict__ hbuf,
                                               const float* __restrict__ W2,
                                               const float* __restrict__ dinv,
                                               ushort* __restrict__ zs_b, int n) {
    __shared__ float sW[HID * OUT_F];      // 15 KB
    __shared__ float sx[G2_ROWS * HID];    // 36 KB
    int tid = threadIdx.x;
    int base = blockIdx.x * G2_ROWS;
    for (int i = tid; i < HID * OUT_F / 4; i += 256)
        ((float4*)sW)[i] = ((const float4*)W2)[i];
    int nt = min(G2_ROWS, n - base);
    for (int i = tid; i < nt * (HID / 4); i += 256) {
        int r = i / 24, kq = i % 24;
        ((float4*)sx)[r * 24 + kq] = ((const float4*)(hbuf + (size_t)(base + r) * HID))[kq];
    }
    __syncthreads();
    if (tid >= 240) return;
    int rt = tid / 10, ct = tid % 10;
    float acc[4][4] = {};
#pragma unroll 1
    for (int k0 = 0; k0 < HID; k0 += 4) {
        float4 xv[4], wv[4];
#pragma unroll
        for (int i = 0; i < 4; i++) xv[i] = *(const float4*)&sx[(rt * 4 + i) * HID + k0];
#pragma unroll
        for (int j = 0; j < 4; j++) wv[j] = *(const float4*)&sW[(k0 + j) * OUT_F + ct * 4];
#pragma unroll
        for (int j = 0; j < 4; j++) {
            float4 w = wv[j];
#pragma unroll
            for (int i = 0; i < 4; i++) {
                float xs = (j == 0) ? xv[i].x : (j == 1) ? xv[i].y : (j == 2) ? xv[i].z : xv[i].w;
                acc[i][0] += xs * w.x;
                acc[i][1] += xs * w.y;
                acc[i][2] += xs * w.z;
                acc[i][3] += xs * w.w;
            }
        }
    }
#pragma unroll
    for (int i = 0; i < 4; i++) {
        int r = rt * 4 + i;
        if (r < nt) {
            int node = base + r;
            float dv = dinv[node];
            ushort4 o = {f2bf(acc[i][0] * dv), f2bf(acc[i][1] * dv),
                         f2bf(acc[i][2] * dv), f2bf(acc[i][3] * dv)};
            *(ushort4*)(zs_b + (size_t)node * OUT_F + ct * 4) = o;
        }
    }
}

// ======================= gather2 + log_softmax, bf16 messages =======================
__global__ __launch_bounds__(256) void k_gather2(const int* __restrict__ offs,
                                                 const int* __restrict__ deg,
                                                 const int* __restrict__ csr,
                                                 const ushort* __restrict__ zs_b,
                                                 const float* __restrict__ dinv,
                                                 const float* __restrict__ b2,
                                                 float* __restrict__ out, int n) {
    int t = blockIdx.x * 256 + threadIdx.x;
    int node = t >> 3, cg = t & 7;
    if (node >= n) return;
    bool act = cg < 5;
    const uint4* zsr = (const uint4*)zs_b;   // 5 uint4 per 40-col row
    float acc[8] = {};
    if (act) {
        uint4 sv = zsr[(size_t)node * 5 + cg];
        acc[0] = bflo(sv.x); acc[1] = bfhi(sv.x);
        acc[2] = bflo(sv.y); acc[3] = bfhi(sv.y);
        acc[4] = bflo(sv.z); acc[5] = bfhi(sv.z);
        acc[6] = bflo(sv.w); acc[7] = bfhi(sv.w);
        int o = offs[node], cnt = deg[node];
        int k = o, kend = o + cnt;
        for (; k + 3 < kend; k += 4) {
            int s0 = csr[k], s1 = csr[k + 1], s2 = csr[k + 2], s3 = csr[k + 3];
            uint4 v0 = zsr[(size_t)s0 * 5 + cg];
            uint4 v1 = zsr[(size_t)s1 * 5 + cg];
            uint4 v2 = zsr[(size_t)s2 * 5 + cg];
            uint4 v3 = zsr[(size_t)s3 * 5 + cg];
            acc[0] += (bflo(v0.x) + bflo(v1.x)) + (bflo(v2.x) + bflo(v3.x));
            acc[1] += (bfhi(v0.x) + bfhi(v1.x)) + (bfhi(v2.x) + bfhi(v3.x));
            acc[2] += (bflo(v0.y) + bflo(v1.y)) + (bflo(v2.y) + bflo(v3.y));
            acc[3] += (bfhi(v0.y) + bfhi(v1.y)) + (bfhi(v2.y) + bfhi(v3.y));
            acc[4] += (bflo(v0.z) + bflo(v1.z)) + (bflo(v2.z) + bflo(v3.z));
            acc[5] += (bfhi(v0.z) + bfhi(v1.z)) + (bfhi(v2.z) + bfhi(v3.z));
            acc[6] += (bflo(v0.w) + bflo(v1.w)) + (bflo(v2.w) + bflo(v3.w));
            acc[7] += (bfhi(v0.w) + bfhi(v1.w)) + (bfhi(v2.w) + bfhi(v3.w));
        }
        for (; k < kend; k++) {
            uint4 v0 = zsr[(size_t)csr[k] * 5 + cg];
            acc[0] += bflo(v0.x); acc[1] += bfhi(v0.x);
            acc[2] += bflo(v0.y); acc[3] += bfhi(v0.y);
            acc[4] += bflo(v0.z); acc[5] += bfhi(v0.z);
            acc[6] += bflo(v0.w); acc[7] += bfhi(v0.w);
        }
    }
    float dv = dinv[node];
    float v[8];
    float m = -INFINITY;
    if (act) {
        int col = cg * 8;
        float4 ba = *(const float4*)(b2 + col);
        float4 bb = *(const float4*)(b2 + col + 4);
        v[0] = acc[0] * dv + ba.x; v[1] = acc[1] * dv + ba.y;
        v[2] = acc[2] * dv + ba.z; v[3] = acc[3] * dv + ba.w;
        v[4] = acc[4] * dv + bb.x; v[5] = acc[5] * dv + bb.y;
        v[6] = acc[6] * dv + bb.z; v[7] = acc[7] * dv + bb.w;
#pragma unroll
        for (int i = 0; i < 8; i++) m = fmaxf(m, v[i]);
    }
    for (int mm = 1; mm < 8; mm <<= 1) m = fmaxf(m, __shfl_xor(m, mm, 8));
    float e = 0.f;
    if (act) {
#pragma unroll
        for (int i = 0; i < 8; i++) e += expf(v[i] - m);
    }
    for (int mm = 1; mm < 8; mm <<= 1) e += __shfl_xor(e, mm, 8);
    float ls = logf(e);
    if (act) {
        int col = cg * 8;
        float4 oa = {v[0] - m - ls, v[1] - m - ls, v[2] - m - ls, v[3] - m - ls};
        float4 ob = {v[4] - m - ls, v[5] - m - ls, v[6] - m - ls, v[7] - m - ls};
        float* op = out + (size_t)node * OUT_F + col;
        *(float4*)op = oa;
        *(float4*)(op + 4) = ob;
    }
}

// ======================= mask MLP (4x4 register tiles, 64 nodes/block, fp32 h) =======================
#define MK_ROWS 64
__global__ __launch_bounds__(256) void k_mask(const float* __restrict__ h,
                                              const float* __restrict__ Wm1,
                                              const float* __restrict__ bm1,
                                              const float* __restrict__ Wm2,
                                              const float* __restrict__ bm2,
                                              float* __restrict__ prob_out,
                                              float* __restrict__ mask_out, int n) {
    __shared__ float sW[HID * MASKD];      // 24 KB
    __shared__ float sh[MK_ROWS * HID];    // 24 KB
    int tid = threadIdx.x;
    int base = blockIdx.x * MK_ROWS;
    for (int i = tid; i < HID * MASKD / 4; i += 256)
        ((float4*)sW)[i] = ((const float4*)Wm1)[i];
    int nt = min(MK_ROWS, n - base);
    for (int i = tid; i < nt * (HID / 4); i += 256) {
        int r = i / 24, kq = i % 24;
        ((float4*)sh)[r * 24 + kq] = ((const float4*)(h + (size_t)(base + r) * HID))[kq];
    }
    __syncthreads();
    int nt4 = tid >> 4, ct = tid & 15;
    float acc[4][4] = {};
#pragma unroll 1
    for (int k0 = 0; k0 < HID; k0 += 4) {
        float4 xv[4], wv[4];
#pragma unroll
        for (int i = 0; i < 4; i++) xv[i] = *(const float4*)&sh[(nt4 * 4 + i) * HID + k0];
#pragma unroll
        for (int j = 0; j < 4; j++) wv[j] = *(const float4*)&sW[(k0 + j) * MASKD + ct * 4];
#pragma unroll
        for (int j = 0; j < 4; j++) {
            float4 w = wv[j];
#pragma unroll
            for (int i = 0; i < 4; i++) {
                float xs = (j == 0) ? xv[i].x : (j == 1) ? xv[i].y : (j == 2) ? xv[i].z : xv[i].w;
                acc[i][0] += xs * w.x;
                acc[i][1] += xs * w.y;
                acc[i][2] += xs * w.z;
                acc[i][3] += xs * w.w;
            }
        }
    }
    float4 b1v = *(const float4*)(bm1 + ct * 4);
    float4 w2v = *(const float4*)(Wm2 + ct * 4);
    float p[4];
#pragma unroll
    for (int i = 0; i < 4; i++) {
        p[i] = fmaxf(acc[i][0] + b1v.x, 0.f) * w2v.x +
               fmaxf(acc[i][1] + b1v.y, 0.f) * w2v.y +
               fmaxf(acc[i][2] + b1v.z, 0.f) * w2v.z +
               fmaxf(acc[i][3] + b1v.w, 0.f) * w2v.w;
    }
    for (int mm = 1; mm < 16; mm <<= 1) {
#pragma unroll
        for (int i = 0; i < 4; i++) p[i] += __shfl_xor(p[i], mm, 16);
    }
    if (ct == 0) {
        float bb = bm2[0];
#pragma unroll
        for (int i = 0; i < 4; i++) {
            int r = nt4 * 4 + i;
            if (r < nt) {
                float tt = p[i] + bb;
                float pr = 1.0f / (1.0f + expf(-tt));
                prob_out[base + r] = pr;
                mask_out[base + r] = (pr > 0.5f) ? 1.0f : 0.0f;
            }
        }
    }
}

extern "C" void kernel_launch(void* const* d_in, const int* in_sizes, int n_in,
                              void* d_out, int out_size, void* d_ws, size_t ws_size,
                              hipStream_t stream) {
    const float* x   = (const float*)d_in[0];
    const int*   ei  = (const int*)d_in[1];
    const float* W1  = (const float*)d_in[2];
    const float* b1  = (const float*)d_in[3];
    const float* W2  = (const float*)d_in[4];
    const float* b2  = (const float*)d_in[5];
    const float* Wm1 = (const float*)d_in[6];
    const float* bm1 = (const float*)d_in[7];
    const float* Wm2 = (const float*)d_in[8];
    const float* bm2 = (const float*)d_in[9];

    int n = in_sizes[0] / IN_F;      // 50000
    int e = in_sizes[1] / 2;         // 800000
    const int* srcp = ei;
    const int* dstp = ei + e;
    int np = (n + PSIZE - 1) >> PBITS;   // 196 partitions (n <= 65536)

    // workspace layout (256B-aligned chunks)
    char* wsb = (char*)d_ws;
    float* dinv = (float*)wsb;            wsb += (((size_t)n * 4) + 255) & ~(size_t)255;
    float* hs = (float*)wsb;              wsb += (((size_t)n * HID * 4) + 255) & ~(size_t)255;
    float* h = (float*)wsb;               wsb += (((size_t)n * HID * 4) + 255) & ~(size_t)255;
    ushort* zs_b = (ushort*)wsb;          wsb += (((size_t)n * OUT_F * 2) + 255) & ~(size_t)255;
    int* deg = (int*)wsb;                 wsb += (((size_t)n * 4) + 255) & ~(size_t)255;
    int* offs = (int*)wsb;                wsb += (((size_t)n * 4) + 255) & ~(size_t)255;
    int* part_total = (int*)wsb;          wsb += 1024;
    int* part_base = (int*)wsb;           wsb += 2048;
    int* part_cursor = (int*)wsb;         wsb += 1024;
    int* csr = (int*)wsb;                 wsb += (((size_t)e * 4) + 255) & ~(size_t)255;
    uint* ebuf = (uint*)wsb;              wsb += (((size_t)e * 4) + 255) & ~(size_t)255;

    float* out    = (float*)d_out;
    float* logits = out;
    float* prob   = out + (size_t)n * OUT_F;
    float* mask   = prob + n;

    int ebl = (e + CHUNK - 1) / CHUNK;

    k_pzero   <<<1, 256, 0, stream>>>(part_total);
    k_pcount  <<<ebl, 256, 0, stream>>>(dstp, part_total, e);
    k_pscan   <<<1, 256, 0, stream>>>(part_total, part_base, part_cursor, np);
    k_bin     <<<ebl, 256, 0, stream>>>(srcp, dstp, part_cursor, ebuf, e);
    k_csr     <<<np, 256, 0, stream>>>(ebuf, part_base, deg, offs, dinv, csr, n);
    k_gemm1   <<<(n + G1_ROWS - 1) / G1_ROWS, 384, 0, stream>>>(x, W1, dinv, hs, n);
    k_gather1 <<<(n * 32 + 255) / 256, 256, 0, stream>>>(offs, deg, csr, hs, dinv, b1, h, n);
    k_gemm2   <<<(n + G2_ROWS - 1) / G2_ROWS, 256, 0, stream>>>(h, W2, dinv, zs_b, n);
    k_gather2 <<<(n * 8 + 255) / 256, 256, 0, stream>>>(offs, deg, csr, zs_b, dinv, b2, logits, n);
    k_mask    <<<(n + MK_ROWS - 1) / MK_ROWS, 256, 0, stream>>>(h, Wm1, bm1, Wm2, bm2, prob, mask, n);
}

// Round 10
// 240.273 us; speedup vs baseline: 1.0920x; 1.0920x over previous
//
#include <hip/hip_runtime.h>
#include <math.h>

#define IN_F  128
#define HID   96
#define OUT_F 40
#define MASKD 64

#define PBITS 8
#define PSIZE 256          // nodes per partition (requires n <= 65536)
#define CHUNK 2048         // edges per workgroup in binning pass
#define ECAP  8192         // fixed edge capacity per partition (mean 4082, sd 64 -> 64 sigma)

typedef unsigned int uint;
typedef unsigned short ushort;

// bf16 helpers. CONSTRAINT (R7 failure): h-path messages (hs) MUST stay fp32 —
// bf16 hs perturbs prob by ~2.5e-3 and flips mask=(prob>0.5) hard bits.
// bf16 is safe ONLY for zs (logits-only path, 5x margin).
__device__ inline float bflo(uint u) { return __uint_as_float(u << 16); }
__device__ inline float bfhi(uint u) { return __uint_as_float(u & 0xffff0000u); }
__device__ inline ushort f2bf(float f) {        // round-to-nearest-even
    uint u = __float_as_uint(f);
    u += 0x7fff + ((u >> 16) & 1);
    return (ushort)(u >> 16);
}

// ======================= partition-local CSR construction =======================
// R10: fixed-capacity partitions (base = p*ECAP) remove the count+scan prepass.
__global__ void k_pinit(int* __restrict__ part_cursor) {
    part_cursor[threadIdx.x] = (int)(threadIdx.x * ECAP);
}

// bin edges into partition-sorted ebuf; packed 4B/edge: src(16b) | dst_local(8b)<<16
__global__ __launch_bounds__(256) void k_bin(const int* __restrict__ src,
                                             const int* __restrict__ dst,
                                             int* __restrict__ part_cursor,
                                             uint* __restrict__ ebuf, int e) {
    __shared__ int hist[256];
    __shared__ int cur[256];
    int tid = threadIdx.x;
    hist[tid] = 0;
    __syncthreads();
    int start = blockIdx.x * CHUNK, end = min(e, start + CHUNK);
    for (int i = start + tid; i < end; i += 256)
        atomicAdd(&hist[dst[i] >> PBITS], 1);
    __syncthreads();
    int hv = hist[tid];
    cur[tid] = hv ? atomicAdd(&part_cursor[tid], hv) : 0;
    __syncthreads();
    for (int i = start + tid; i < end; i += 256) {
        int d = dst[i];
        int pos = atomicAdd(&cur[d >> PBITS], 1);
        ebuf[pos] = (uint)src[i] | ((uint)(d & (PSIZE - 1)) << 16);
    }
}

// one workgroup per partition: LDS count + scan + LDS-cursor fill; emits deg/offs/dinv.
// eend comes from the post-bin cursor (= p*ECAP + count_p).
__global__ __launch_bounds__(256) void k_csr(const uint* __restrict__ ebuf,
                                             const int* __restrict__ part_cursor,
                                             int* __restrict__ deg, int* __restrict__ offs,
                                             float* __restrict__ dinv,
                                             int* __restrict__ csr, int n) {
    __shared__ int cnt[256];
    __shared__ int tmp[256];
    __shared__ int cur[256];
    int tid = threadIdx.x;
    int p = blockIdx.x;
    int ebase = p * ECAP, eend = part_cursor[p];
    cnt[tid] = 0;
    __syncthreads();
    for (int i = ebase + tid; i < eend; i += 256)
        atomicAdd(&cnt[(ebuf[i] >> 16) & 255], 1);
    __syncthreads();
    int v = cnt[tid];
    tmp[tid] = v;
    __syncthreads();
    for (int d = 1; d < 256; d <<= 1) {
        int t = (tid >= d) ? tmp[tid - d] : 0;
        __syncthreads();
        tmp[tid] += t;
        __syncthreads();
    }
    int goff = ebase + (tmp[tid] - v);
    int node = p * PSIZE + tid;
    if (node < n) {
        deg[node] = v;
        offs[node] = goff;
        dinv[node] = rsqrtf((float)(v + 1));
    }
    cur[tid] = goff;
    __syncthreads();
    for (int i = ebase + tid; i < eend; i += 256) {
        uint ed = ebuf[i];
        int pos = atomicAdd(&cur[(ed >> 16) & 255], 1);
        csr[pos] = (int)(ed & 0xffffu);
    }
}

// ======================= GEMM1: hs = (x @ W1) * dinv[row] ===========================================
// R9 post-mortem: 4x4 tile is LDS-throughput-bound (2.0 B-LDS/FMA vs 85 B/cyc pipe -> VALU capped
// ~33%; occupancy tuning was a no-op). R10: 8x8 register tile, x read from GLOBAL (L1/L2 pipe),
// only W in LDS (0.5 B-LDS/FMA) -> VALU-bound. #pragma unroll 1 load-bearing (R3 spill).
#define G1_ROWS 128
__global__ __launch_bounds__(192) void k_gemm1(const float* __restrict__ x,
                                               const float* __restrict__ W1,
                                               const float* __restrict__ dinv,
                                               float* __restrict__ hs, int n) {
    __shared__ float sW[IN_F * HID];   // 48 KB, [k][c]
    int tid = threadIdx.x;
    for (int i = tid; i < IN_F * HID / 4; i += 192)
        ((float4*)sW)[i] = ((const float4*)W1)[i];
    __syncthreads();
    int base = blockIdx.x * G1_ROWS;
    int rt = tid / 12, ct = tid % 12;   // rt 0..15 (8 rows each), ct 0..11 (8 cols each)
    int r0 = base + rt * 8;
    const float* xp[8];
#pragma unroll
    for (int i = 0; i < 8; i++) {
        int r = min(r0 + i, n - 1);     // clamp: OOB rows load row n-1, stores guarded
        xp[i] = x + (size_t)r * IN_F;
    }
    float acc[8][8] = {};
#pragma unroll 1
    for (int k0 = 0; k0 < IN_F; k0 += 4) {
        float4 xv[8];
#pragma unroll
        for (int i = 0; i < 8; i++) xv[i] = *(const float4*)(xp[i] + k0);
        float4 wa[4], wb[4];
#pragma unroll
        for (int j = 0; j < 4; j++) {
            wa[j] = *(const float4*)&sW[(k0 + j) * HID + ct * 8];
            wb[j] = *(const float4*)&sW[(k0 + j) * HID + ct * 8 + 4];
        }
#pragma unroll
        for (int j = 0; j < 4; j++) {
#pragma unroll
            for (int i = 0; i < 8; i++) {
                float xs = (j == 0) ? xv[i].x : (j == 1) ? xv[i].y : (j == 2) ? xv[i].z : xv[i].w;
                acc[i][0] += xs * wa[j].x; acc[i][1] += xs * wa[j].y;
                acc[i][2] += xs * wa[j].z; acc[i][3] += xs * wa[j].w;
                acc[i][4] += xs * wb[j].x; acc[i][5] += xs * wb[j].y;
                acc[i][6] += xs * wb[j].z; acc[i][7] += xs * wb[j].w;
            }
        }
    }
#pragma unroll
    for (int i = 0; i < 8; i++) {
        int r = r0 + i;
        if (r < n) {
            float dv = dinv[r];
            float4 o1 = {acc[i][0] * dv, acc[i][1] * dv, acc[i][2] * dv, acc[i][3] * dv};
            float4 o2 = {acc[i][4] * dv, acc[i][5] * dv, acc[i][6] * dv, acc[i][7] * dv};
            float* hp = hs + (size_t)r * HID + ct * 8;
            *(float4*)hp = o1;
            *(float4*)(hp + 4) = o2;
        }
    }
}

// ======================= gather1 + relu: h = relu(agg * dinv + b1)  (fp32 messages) =================
__global__ __launch_bounds__(256) void k_gather1(const int* __restrict__ offs,
                                                 const int* __restrict__ deg,
                                                 const int* __restrict__ csr,
                                                 const float* __restrict__ hs,
                                                 const float* __restrict__ dinv,
                                                 const float* __restrict__ b1,
                                                 float* __restrict__ h, int n) {
    int t = blockIdx.x * 256 + threadIdx.x;
    int node = t >> 5, cg = t & 31;
    if (node >= n || cg >= 24) return;
    int o = offs[node], cnt = deg[node];
    size_t col = (size_t)cg * 4;
    float4 acc = *(const float4*)(hs + (size_t)node * HID + col);  // self-loop term
    int k = o, kend = o + cnt;
    for (; k + 3 < kend; k += 4) {
        int s0 = csr[k], s1 = csr[k + 1], s2 = csr[k + 2], s3 = csr[k + 3];
        const float4 v0 = *(const float4*)(hs + (size_t)s0 * HID + col);
        const float4 v1 = *(const float4*)(hs + (size_t)s1 * HID + col);
        const float4 v2 = *(const float4*)(hs + (size_t)s2 * HID + col);
        const float4 v3 = *(const float4*)(hs + (size_t)s3 * HID + col);
        acc.x += (v0.x + v1.x) + (v2.x + v3.x);
        acc.y += (v0.y + v1.y) + (v2.y + v3.y);
        acc.z += (v0.z + v1.z) + (v2.z + v3.z);
        acc.w += (v0.w + v1.w) + (v2.w + v3.w);
    }
    for (; k < kend; k++) {
        int s0 = csr[k];
        const float4 v0 = *(const float4*)(hs + (size_t)s0 * HID + col);
        acc.x += v0.x; acc.y += v0.y; acc.z += v0.z; acc.w += v0.w;
    }
    float dv = dinv[node];
    float4 bv = *(const float4*)(b1 + col);
    float4 o4 = {fmaxf(acc.x * dv + bv.x, 0.f), fmaxf(acc.y * dv + bv.y, 0.f),
                 fmaxf(acc.z * dv + bv.z, 0.f), fmaxf(acc.w * dv + bv.w, 0.f)};
    *(float4*)(h + (size_t)node * HID + col) = o4;
}

// ======================= fused tail: zs = bf16((h@W2)*dinv)  AND  mask MLP ==========================
// One staging of h feeds both phases (R9: k_mask alone re-read 19.2MB of h).
#define T_ROWS 64
__global__ __launch_bounds__(256) void k_tail(const float* __restrict__ h,
                                              const float* __restrict__ W2,
                                              const float* __restrict__ dinv,
                                              const float* __restrict__ Wm1,
                                              const float* __restrict__ bm1,
                                              const float* __restrict__ Wm2,
                                              const float* __restrict__ bm2,
                                              ushort* __restrict__ zs_b,
                                              float* __restrict__ prob_out,
                                              float* __restrict__ mask_out, int n) {
    __shared__ float sW2[HID * OUT_F];   // 15 KB, [k][c]
    __shared__ float sWm[HID * MASKD];   // 24 KB, [k][c]
    __shared__ float sh[T_ROWS * HID];   // 24 KB, [r][k]
    int tid = threadIdx.x;
    int base = blockIdx.x * T_ROWS;
    for (int i = tid; i < HID * OUT_F / 4; i += 256)
        ((float4*)sW2)[i] = ((const float4*)W2)[i];
    for (int i = tid; i < HID * MASKD / 4; i += 256)
        ((float4*)sWm)[i] = ((const float4*)Wm1)[i];
    int nt = min(T_ROWS, n - base);
    for (int i = tid; i < nt * (HID / 4); i += 256) {
        int r = i / 24, kq = i % 24;
        ((float4*)sh)[r * 24 + kq] = ((const float4*)(h + (size_t)(base + r) * HID))[kq];
    }
    __syncthreads();

    // ---- phase A: zs (4x4 tiles; rt 0..15 x ct 0..9 = 160 active threads) ----
    if (tid < 160) {
        int rt = tid / 10, ct = tid % 10;
        float acc[4][4] = {};
#pragma unroll 1
        for (int k0 = 0; k0 < HID; k0 += 4) {
            float4 xv[4], wv[4];
#pragma unroll
            for (int i = 0; i < 4; i++) xv[i] = *(const float4*)&sh[(rt * 4 + i) * HID + k0];
#pragma unroll
            for (int j = 0; j < 4; j++) wv[j] = *(const float4*)&sW2[(k0 + j) * OUT_F + ct * 4];
#pragma unroll
            for (int j = 0; j < 4; j++) {
                float4 w = wv[j];
#pragma unroll
                for (int i = 0; i < 4; i++) {
                    float xs = (j == 0) ? xv[i].x : (j == 1) ? xv[i].y : (j == 2) ? xv[i].z : xv[i].w;
                    acc[i][0] += xs * w.x;
                    acc[i][1] += xs * w.y;
                    acc[i][2] += xs * w.z;
                    acc[i][3] += xs * w.w;
                }
            }
        }
#pragma unroll
        for (int i = 0; i < 4; i++) {
            int r = rt * 4 + i;
            if (r < nt) {
                int node = base + r;
                float dv = dinv[node];
                ushort4 o = {f2bf(acc[i][0] * dv), f2bf(acc[i][1] * dv),
                             f2bf(acc[i][2] * dv), f2bf(acc[i][3] * dv)};
                *(ushort4*)(zs_b + (size_t)node * OUT_F + ct * 4) = o;
            }
        }
    }

    // ---- phase B: mask MLP (all 256 threads; nt4 0..15 x ct16 0..15) ----
    {
        int nt4 = tid >> 4, ct = tid & 15;
        float acc[4][4] = {};
#pragma unroll 1
        for (int k0 = 0; k0 < HID; k0 += 4) {
            float4 xv[4], wv[4];
#pragma unroll
            for (int i = 0; i < 4; i++) xv[i] = *(const float4*)&sh[(nt4 * 4 + i) * HID + k0];
#pragma unroll
            for (int j = 0; j < 4; j++) wv[j] = *(const float4*)&sWm[(k0 + j) * MASKD + ct * 4];
#pragma unroll
            for (int j = 0; j < 4; j++) {
                float4 w = wv[j];
#pragma unroll
                for (int i = 0; i < 4; i++) {
                    float xs = (j == 0) ? xv[i].x : (j == 1) ? xv[i].y : (j == 2) ? xv[i].z : xv[i].w;
                    acc[i][0] += xs * w.x;
                    acc[i][1] += xs * w.y;
                    acc[i][2] += xs * w.z;
                    acc[i][3] += xs * w.w;
                }
            }
        }
        float4 b1v = *(const float4*)(bm1 + ct * 4);
        float4 w2v = *(const float4*)(Wm2 + ct * 4);
        float p[4];
#pragma unroll
        for (int i = 0; i < 4; i++) {
            p[i] = fmaxf(acc[i][0] + b1v.x, 0.f) * w2v.x +
                   fmaxf(acc[i][1] + b1v.y, 0.f) * w2v.y +
                   fmaxf(acc[i][2] + b1v.z, 0.f) * w2v.z +
                   fmaxf(acc[i][3] + b1v.w, 0.f) * w2v.w;
        }
        for (int mm = 1; mm < 16; mm <<= 1) {
#pragma unroll
            for (int i = 0; i < 4; i++) p[i] += __shfl_xor(p[i], mm, 16);
        }
        if (ct == 0) {
            float bb = bm2[0];
#pragma unroll
            for (int i = 0; i < 4; i++) {
                int r = nt4 * 4 + i;
                if (r < nt) {
                    float tt = p[i] + bb;
                    float pr = 1.0f / (1.0f + expf(-tt));
                    prob_out[base + r] = pr;
                    mask_out[base + r] = (pr > 0.5f) ? 1.0f : 0.0f;
                }
            }
        }
    }
}

// ======================= gather2 + log_softmax, bf16 messages =======================
__global__ __launch_bounds__(256) void k_gather2(const int* __restrict__ offs,
                                                 const int* __restrict__ deg,
                                                 const int* __restrict__ csr,
                                                 const ushort* __restrict__ zs_b,
                                                 const float* __restrict__ dinv,
                                                 const float* __restrict__ b2,
                                                 float* __restrict__ out, int n) {
    int t = blockIdx.x * 256 + threadIdx.x;
    int node = t >> 3, cg = t & 7;
    if (node >= n) return;
    bool act = cg < 5;
    const uint4* zsr = (const uint4*)zs_b;   // 5 uint4 per 40-col row
    float acc[8] = {};
    if (act) {
        uint4 sv = zsr[(size_t)node * 5 + cg];
        acc[0] = bflo(sv.x); acc[1] = bfhi(sv.x);
        acc[2] = bflo(sv.y); acc[3] = bfhi(sv.y);
        acc[4] = bflo(sv.z); acc[5] = bfhi(sv.z);
        acc[6] = bflo(sv.w); acc[7] = bfhi(sv.w);
        int o = offs[node], cnt = deg[node];
        int k = o, kend = o + cnt;
        for (; k + 3 < kend; k += 4) {
            int s0 = csr[k], s1 = csr[k + 1], s2 = csr[k + 2], s3 = csr[k + 3];
            uint4 v0 = zsr[(size_t)s0 * 5 + cg];
            uint4 v1 = zsr[(size_t)s1 * 5 + cg];
            uint4 v2 = zsr[(size_t)s2 * 5 + cg];
            uint4 v3 = zsr[(size_t)s3 * 5 + cg];
            acc[0] += (bflo(v0.x) + bflo(v1.x)) + (bflo(v2.x) + bflo(v3.x));
            acc[1] += (bfhi(v0.x) + bfhi(v1.x)) + (bfhi(v2.x) + bfhi(v3.x));
            acc[2] += (bflo(v0.y) + bflo(v1.y)) + (bflo(v2.y) + bflo(v3.y));
            acc[3] += (bfhi(v0.y) + bfhi(v1.y)) + (bfhi(v2.y) + bfhi(v3.y));
            acc[4] += (bflo(v0.z) + bflo(v1.z)) + (bflo(v2.z) + bflo(v3.z));
            acc[5] += (bfhi(v0.z) + bfhi(v1.z)) + (bfhi(v2.z) + bfhi(v3.z));
            acc[6] += (bflo(v0.w) + bflo(v1.w)) + (bflo(v2.w) + bflo(v3.w));
            acc[7] += (bfhi(v0.w) + bfhi(v1.w)) + (bfhi(v2.w) + bfhi(v3.w));
        }
        for (; k < kend; k++) {
            uint4 v0 = zsr[(size_t)csr[k] * 5 + cg];
            acc[0] += bflo(v0.x); acc[1] += bfhi(v0.x);
            acc[2] += bflo(v0.y); acc[3] += bfhi(v0.y);
            acc[4] += bflo(v0.z); acc[5] += bfhi(v0.z);
            acc[6] += bflo(v0.w); acc[7] += bfhi(v0.w);
        }
    }
    float dv = dinv[node];
    float v[8];
    float m = -INFINITY;
    if (act) {
        int col = cg * 8;
        float4 ba = *(const float4*)(b2 + col);
        float4 bb = *(const float4*)(b2 + col + 4);
        v[0] = acc[0] * dv + ba.x; v[1] = acc[1] * dv + ba.y;
        v[2] = acc[2] * dv + ba.z; v[3] = acc[3] * dv + ba.w;
        v[4] = acc[4] * dv + bb.x; v[5] = acc[5] * dv + bb.y;
        v[6] = acc[6] * dv + bb.z; v[7] = acc[7] * dv + bb.w;
#pragma unroll
        for (int i = 0; i < 8; i++) m = fmaxf(m, v[i]);
    }
    for (int mm = 1; mm < 8; mm <<= 1) m = fmaxf(m, __shfl_xor(m, mm, 8));
    float e = 0.f;
    if (act) {
#pragma unroll
        for (int i = 0; i < 8; i++) e += expf(v[i] - m);
    }
    for (int mm = 1; mm < 8; mm <<= 1) e += __shfl_xor(e, mm, 8);
    float ls = logf(e);
    if (act) {
        int col = cg * 8;
        float4 oa = {v[0] - m - ls, v[1] - m - ls, v[2] - m - ls, v[3] - m - ls};
        float4 ob = {v[4] - m - ls, v[5] - m - ls, v[6] - m - ls, v[7] - m - ls};
        float* op = out + (size_t)node * OUT_F + col;
        *(float4*)op = oa;
        *(float4*)(op + 4) = ob;
    }
}

extern "C" void kernel_launch(void* const* d_in, const int* in_sizes, int n_in,
                              void* d_out, int out_size, void* d_ws, size_t ws_size,
                              hipStream_t stream) {
    const float* x   = (const float*)d_in[0];
    const int*   ei  = (const int*)d_in[1];
    const float* W1  = (const float*)d_in[2];
    const float* b1  = (const float*)d_in[3];
    const float* W2  = (const float*)d_in[4];
    const float* b2  = (const float*)d_in[5];
    const float* Wm1 = (const float*)d_in[6];
    const float* bm1 = (const float*)d_in[7];
    const float* Wm2 = (const float*)d_in[8];
    const float* bm2 = (const float*)d_in[9];

    int n = in_sizes[0] / IN_F;      // 50000
    int e = in_sizes[1] / 2;         // 800000
    const int* srcp = ei;
    const int* dstp = ei + e;
    int np = (n + PSIZE - 1) >> PBITS;   // 196 partitions (n <= 65536)

    // workspace layout (256B-aligned chunks)
    char* wsb = (char*)d_ws;
    float* dinv = (float*)wsb;            wsb += (((size_t)n * 4) + 255) & ~(size_t)255;
    float* hs = (float*)wsb;              wsb += (((size_t)n * HID * 4) + 255) & ~(size_t)255;
    float* h = (float*)wsb;               wsb += (((size_t)n * HID * 4) + 255) & ~(size_t)255;
    ushort* zs_b = (ushort*)wsb;          wsb += (((size_t)n * OUT_F * 2) + 255) & ~(size_t)255;
    int* deg = (int*)wsb;                 wsb += (((size_t)n * 4) + 255) & ~(size_t)255;
    int* offs = (int*)wsb;                wsb += (((size_t)n * 4) + 255) & ~(size_t)255;
    int* part_cursor = (int*)wsb;         wsb += 1024;
    int* csr = (int*)wsb;                 wsb += (((size_t)np * ECAP * 4) + 255) & ~(size_t)255;
    uint* ebuf = (uint*)wsb;              wsb += (((size_t)np * ECAP * 4) + 255) & ~(size_t)255;

    float* out    = (float*)d_out;
    float* logits = out;
    float* prob   = out + (size_t)n * OUT_F;
    float* mask   = prob + n;

    int ebl = (e + CHUNK - 1) / CHUNK;

    k_pinit   <<<1, 256, 0, stream>>>(part_cursor);
    k_bin     <<<ebl, 256, 0, stream>>>(srcp, dstp, part_cursor, ebuf, e);
    k_csr     <<<np, 256, 0, stream>>>(ebuf, part_cursor, deg, offs, dinv, csr, n);
    k_gemm1   <<<(n + G1_ROWS - 1) / G1_ROWS, 192, 0, stream>>>(x, W1, dinv, hs, n);
    k_gather1 <<<(n * 32 + 255) / 256, 256, 0, stream>>>(offs, deg, csr, hs, dinv, b1, h, n);
    k_tail    <<<(n + T_ROWS - 1) / T_ROWS, 256, 0, stream>>>(h, W2, dinv, Wm1, bm1, Wm2, bm2,
                                                              zs_b, prob, mask, n);
    k_gather2 <<<(n * 8 + 255) / 256, 256, 0, stream>>>(offs, deg, csr, zs_b, dinv, b2, logits, n);
}